// Round 6
// baseline (292.263 us; speedup 1.0000x reference)
//
#include <hip/hip_runtime.h>
#include <stdint.h>

// BinaryLinear: out[8192,4096] = x @ W^T + sign(bias); W,b in {-1,+1}.
// Round 6: 32x32x16 MFMA port, FIXED: wave->row decomposition must keep each
// Mh/Nh quadrant inside its staging half (round 5 put wr=0's Mh=1 rows in
// half 0, racing phase-2's STAGE_A). A row = Mh*128 + wr*64 + m*32 + l31;
// B row = Nh*128 + wc*32 + l31 — identical liveness to the passing round 4.

#define M_DIM 8192
#define N_DIM 4096
#define K_DIM 4096
#define NKT   (K_DIM / 64)         // 64 K-tiles
#define KROW  ((size_t)K_DIM * 2)  // row bytes of bf16 operand = 8192

typedef unsigned short ushort_t;
typedef __bf16 bf16x8 __attribute__((ext_vector_type(8)));
typedef float  f32x16 __attribute__((ext_vector_type(16)));
typedef ushort_t ushort4v __attribute__((ext_vector_type(4)));

static __device__ __forceinline__ ushort_t f32_to_bf16_rne(float f) {
    unsigned u = __builtin_bit_cast(unsigned, f);
    unsigned r = 0x7FFFu + ((u >> 16) & 1u);
    return (ushort_t)((u + r) >> 16);
}

__global__ __launch_bounds__(256) void cvt_x_kernel(const float* __restrict__ x,
                                                    ushort_t* __restrict__ xb) {
    size_t i = ((size_t)blockIdx.x * 256 + threadIdx.x) * 4;
    float4 v = *reinterpret_cast<const float4*>(x + i);
    ushort4v o;
    o.x = f32_to_bf16_rne(v.x);
    o.y = f32_to_bf16_rne(v.y);
    o.z = f32_to_bf16_rne(v.z);
    o.w = f32_to_bf16_rne(v.w);
    *reinterpret_cast<ushort4v*>(xb + i) = o;
}

__global__ __launch_bounds__(256) void cvt_w_kernel(const float* __restrict__ w,
                                                    ushort_t* __restrict__ wb) {
    size_t i = ((size_t)blockIdx.x * 256 + threadIdx.x) * 4;
    float4 v = *reinterpret_cast<const float4*>(w + i);
    ushort4v o;
    o.x = (v.x >= 0.f) ? 0x3F80u : 0xBF80u;
    o.y = (v.y >= 0.f) ? 0x3F80u : 0xBF80u;
    o.z = (v.z >= 0.f) ? 0x3F80u : 0xBF80u;
    o.w = (v.w >= 0.f) ? 0x3F80u : 0xBF80u;
    *reinterpret_cast<ushort4v*>(wb + i) = o;
}

static __device__ __forceinline__ void gload_lds16(const void* g, void* s) {
    __builtin_amdgcn_global_load_lds(
        (const __attribute__((address_space(1))) void*)(g),
        (__attribute__((address_space(3))) void*)(s),
        16, 0, 0);
}

// LDS geometry: buf b at b*65536; A region +0 (32KB = 256 rows x 128B),
// B region +32768. Half h = rows h*128 = bytes [h*16384, +16384).
// Swizzle involution within region: P = L ^ (((L>>7)&7)<<4).

#define STAGE_A(bufbase, h, kt) do {                                        \
    char* _d = (bufbase) + (h)*16384 + w*1024;                              \
    gload_lds16(srcA0 + (size_t)(h)*1048576 + (size_t)(kt)*128, _d);        \
    gload_lds16(srcA1 + (size_t)(h)*1048576 + (size_t)(kt)*128, _d + 8192); \
} while (0)

#define STAGE_B(bufbase, h, kt) do {                                        \
    char* _d = (bufbase) + 32768 + (h)*16384 + w*1024;                      \
    gload_lds16(srcB0 + (size_t)(h)*1048576 + (size_t)(kt)*128, _d);        \
    gload_lds16(srcB1 + (size_t)(h)*1048576 + (size_t)(kt)*128, _d + 8192); \
} while (0)

// A fragments, one Mh half: 8 x ds_read_b128 (kk outer = consumption order).
// Lane l holds A[row = Mh*128 + wr*64 + m*32 + (l&31)][k = kk*16 + (l>>5)*8 + j].
#define LDA8(base, Mh, areg) do {                                           \
    _Pragma("unroll") for (int kk = 0; kk < 4; ++kk)                        \
    _Pragma("unroll") for (int m = 0; m < 2; ++m)                           \
        areg[m][kk] = *(const bf16x8*)((base) + aoff + sxk[kk]              \
                                       + (Mh)*16384 + m*4096);              \
} while (0)

// B fragments, one Nh half: 4 x ds_read_b128.
// Lane l holds B[row = Nh*128 + wc*32 + (l&31)][same k map].
#define LDB4(base, Nh, breg) do {                                           \
    _Pragma("unroll") for (int kk = 0; kk < 4; ++kk)                        \
        breg[kk] = *(const bf16x8*)((base) + boff + sxk[kk] + (Nh)*16384);  \
} while (0)

// 8 MFMA; kk-outer -> dependent acc reuse separated by independent ops.
#define MM8(areg, breg, accq) do {                                          \
    __builtin_amdgcn_s_setprio(1);                                          \
    _Pragma("unroll") for (int kk = 0; kk < 4; ++kk)                        \
    _Pragma("unroll") for (int m = 0; m < 2; ++m)                           \
        accq[m] = __builtin_amdgcn_mfma_f32_32x32x16_bf16(                  \
            areg[m][kk], breg[kk], accq[m], 0, 0, 0);                       \
    __builtin_amdgcn_s_setprio(0);                                          \
} while (0)

#define BAR() __builtin_amdgcn_s_barrier()

// One K-tile = 4 phases (quadrants); region liveness == round 4.
#define TILE4(curb, othb, kt, g) do {                                       \
    /* phase 1: (Mh0,Nh0) */                                                \
    LDA8((curb), 0, a); LDB4((curb), 0, b0);                                \
    STAGE_B((othb), 1, (kt) + 1);                                           \
    BAR();                                                                  \
    MM8(a, b0, acc[0][0]);                                                  \
    BAR();                                                                  \
    /* phase 2: (Mh0,Nh1) */                                                \
    LDB4((curb), 1, b1);                                                    \
    if (g) STAGE_A((curb), 0, (kt) + 2);                                    \
    BAR();                                                                  \
    MM8(a, b1, acc[0][1]);                                                  \
    BAR();                                                                  \
    /* phase 3: (Mh1,Nh1) */                                                \
    LDA8((curb), 1, a);                                                     \
    if (g) STAGE_B((curb), 0, (kt) + 2);                                    \
    BAR();                                                                  \
    MM8(a, b1, acc[1][1]);                                                  \
    BAR();                                                                  \
    /* phase 4: (Mh1,Nh0) — a from ph3, b0 from ph1, no ds_reads */         \
    if (g) STAGE_A((curb), 1, (kt) + 2);                                    \
    BAR();                                                                  \
    MM8(a, b0, acc[1][0]);                                                  \
} while (0)

__global__ __launch_bounds__(512, 2)
void bgemm8_kernel(const ushort_t* __restrict__ A, const ushort_t* __restrict__ Bm,
                   const float* __restrict__ bias, float* __restrict__ C) {
    __shared__ char lds[131072];

    const int t = threadIdx.x;
    const int w = t >> 6;          // wave 0..7
    const int l = t & 63;
    const int wr = w >> 2;         // 0..1 (M)
    const int wc = w & 3;          // 0..3 (N)

    // XCD swizzle: 512 blocks, 512 % 8 == 0 -> bijective
    const int bid = blockIdx.x;
    const int wg  = (bid & 7) * 64 + (bid >> 3);
    const int tn  = wg & 15;       // N tiles: 4096/256 = 16
    const int tm  = wg >> 4;       // M tiles: 8192/256 = 32

    // ---- staging: thread t, call j covers physical bytes [(j*512+t)*16,+16)
    // of a 16KB half-tile; invert swizzle for the global source.
    int srow[2], skb[2];
#pragma unroll
    for (int j = 0; j < 2; ++j) {
        int p = (j * 512 + t) * 16;
        int L = p ^ (((p >> 7) & 7) << 4);
        srow[j] = L >> 7;
        skb[j]  = L & 127;
    }
    const char* srcA0 = (const char*)A  + ((size_t)(tm * 256) + srow[0]) * KROW + skb[0];
    const char* srcA1 = (const char*)A  + ((size_t)(tm * 256) + srow[1]) * KROW + skb[1];
    const char* srcB0 = (const char*)Bm + ((size_t)(tn * 256) + srow[0]) * KROW + skb[0];
    const char* srcB1 = (const char*)Bm + ((size_t)(tn * 256) + srow[1]) * KROW + skb[1];

    // ---- fragment addressing (32x32x16): logical col bytes
    // c = kk*32 + (l>>5)*16; physical = c ^ ((row&7)<<4), row&7 == l&7.
    const int l31 = l & 31;
    const int kh5 = l >> 5;
    const int x7  = (l & 7) << 4;
    int sxk[4];
#pragma unroll
    for (int kk = 0; kk < 4; ++kk)
        sxk[kk] = (kk * 32 + kh5 * 16) ^ x7;
    const int aoff = (wr * 64 + l31) * 128;            // A: rows wr*64+[0,64) of each half
    const int boff = 32768 + (wc * 32 + l31) * 128;    // B: rows wc*32+[0,32) of each half

    char* const buf0 = lds;
    char* const buf1 = lds + 65536;

    // ---- prologue: tile0 -> buf0 (4 halves); tile1 A0,B0,A1 -> buf1
    STAGE_A(buf0, 0, 0); STAGE_B(buf0, 0, 0); STAGE_A(buf0, 1, 0); STAGE_B(buf0, 1, 0);
    STAGE_A(buf1, 0, 1); STAGE_B(buf1, 0, 1); STAGE_A(buf1, 1, 1);
    asm volatile("s_waitcnt vmcnt(6)" ::: "memory");
    BAR();

    f32x16 acc[2][2][2] = {};      // [Mh][Nh][m], 128 VGPRs
    bf16x8 a[2][4], b0[4], b1[4];

#pragma unroll 1
    for (int kt = 0; kt < NKT; kt += 2) {
        const bool g = (kt < NKT - 2);   // stage-(+2) guard, uniform

        // ---- even tile kt: buf0 current, buf1 other
        TILE4(buf0, buf1, kt, g);
        if (g)  asm volatile("s_waitcnt vmcnt(6)" ::: "memory");
        else    asm volatile("s_waitcnt vmcnt(0)" ::: "memory");
        BAR();

        // ---- odd tile kt+1: buf1 current, buf0 other
        TILE4(buf1, buf0, kt + 1, g);
        if (g) asm volatile("s_waitcnt vmcnt(6)" ::: "memory");
        BAR();
    }

    // ---- epilogue: 32x32 C/D layout (verified m74/m101):
    // col = lane&31, row = (reg&3) + 8*(reg>>2) + 4*(lane>>5)
    const int c0 = tn * 256 + wc * 32 + l31;
    const int r0 = tm * 256 + wr * 64 + 4 * kh5;
    float bs[2];
#pragma unroll
    for (int Nh = 0; Nh < 2; ++Nh)
        bs[Nh] = (bias[c0 + Nh * 128] >= 0.f) ? 1.f : -1.f;
#pragma unroll
    for (int Mh = 0; Mh < 2; ++Mh)
#pragma unroll
    for (int Nh = 0; Nh < 2; ++Nh)
#pragma unroll
    for (int m = 0; m < 2; ++m) {
        const int col = c0 + Nh * 128;
#pragma unroll
        for (int reg = 0; reg < 16; ++reg) {
            const int row = r0 + Mh * 128 + m * 32 + (reg & 3) + 8 * (reg >> 2);
            C[(size_t)row * N_DIM + col] = acc[Mh][Nh][m][reg] + bs[Nh];
        }
    }
}

extern "C" void kernel_launch(void* const* d_in, const int* in_sizes, int n_in,
                              void* d_out, int out_size, void* d_ws, size_t ws_size,
                              hipStream_t stream) {
    const float* x    = (const float*)d_in[0];
    const float* wgt  = (const float*)d_in[1];
    const float* bias = (const float*)d_in[2];
    float* out = (float*)d_out;

    ushort_t* xb = (ushort_t*)d_ws;                       // 64 MB
    ushort_t* wb = xb + (size_t)M_DIM * K_DIM;            // 32 MB

    cvt_x_kernel<<<(M_DIM * (size_t)K_DIM) / 4 / 256, 256, 0, stream>>>(x, xb);
    cvt_w_kernel<<<(N_DIM * (size_t)K_DIM) / 4 / 256, 256, 0, stream>>>(wgt, wb);

    dim3 grid((M_DIM / 256) * (N_DIM / 256));             // 32*16 = 512
    bgemm8_kernel<<<grid, 512, 0, stream>>>(xb, wb, bias, out);
}